// Round 2
// baseline (99.795 us; speedup 1.0000x reference)
//
#include <hip/hip_runtime.h>
#include <math.h>
#include <float.h>
#include <limits.h>

#define QPB 32      // queries per block
#define QT  4       // queries per thread
#define TM  2048    // reference points staged per LDS tile
#define KNN 3

__device__ __forceinline__ void ins3(float d, int ix,
    float& d0, float& d1, float& d2, int& i0, int& i1, int& i2)
{
    bool l2 = (d < d2) || (d == d2 && ix < i2);
    if (l2) {
        bool l1 = (d < d1) || (d == d1 && ix < i1);
        if (l1) {
            d2 = d1; i2 = i1;
            bool l0 = (d < d0) || (d == d0 && ix < i0);
            if (l0) { d1 = d0; i1 = i0; d0 = d; i0 = ix; }
            else    { d1 = d;  i1 = ix; }
        } else { d2 = d; i2 = ix; }
    }
}

__launch_bounds__(256, 2)
__global__ void knn_flow_kernel(const float* __restrict__ pc0,
                                const float* __restrict__ pc1,
                                const float* __restrict__ flow1,
                                const float* __restrict__ pose0,
                                const float* __restrict__ pose1,
                                float* __restrict__ out,
                                int B, int N, int M)
{
    __shared__ float4 tile[TM];
    __shared__ float  mdl[4][8][QT][KNN];
    __shared__ int    mil[4][8][QT][KNN];

    const int tid   = threadIdx.x;
    const int qlane = tid & 7;          // 0..7 query lane
    const int s     = tid >> 3;         // 0..31 global stripe
    const int b     = blockIdx.y;
    const int qb    = blockIdx.x * QPB;

    // ---- relative pose: pose_0to1 = inv(pose1) @ pose0 (SE3 analytic) ----
    const float* P0 = pose0 + b * 16;
    const float* P1 = pose1 + b * 16;
    float R[3][3], tv[3];
    {
        float dt0 = P0[3]  - P1[3];
        float dt1 = P0[7]  - P1[7];
        float dt2 = P0[11] - P1[11];
        #pragma unroll
        for (int i = 0; i < 3; ++i) {
            float a0 = P1[i], a1 = P1[4 + i], a2 = P1[8 + i]; // column i of R1
            #pragma unroll
            for (int j = 0; j < 3; ++j)
                R[i][j] = fmaf(a2, P0[8 + j], fmaf(a1, P0[4 + j], a0 * P0[j]));
            tv[i] = fmaf(a2, dt2, fmaf(a1, dt1, a0 * dt0));
        }
    }

    // ---- transform this thread's QT queries; lanes tid<8 write pose_flow ----
    float qx[QT], qy[QT], qz[QT], q2[QT];
    #pragma unroll
    for (int t = 0; t < QT; ++t) {
        int qg0 = qb + qlane * QT + t;
        bool valid = qg0 < N;
        int qg = valid ? qg0 : (N - 1);
        const float px = pc0[(size_t)(b * N + qg) * 3 + 0];
        const float py = pc0[(size_t)(b * N + qg) * 3 + 1];
        const float pz = pc0[(size_t)(b * N + qg) * 3 + 2];
        qx[t] = fmaf(R[0][2], pz, fmaf(R[0][1], py, R[0][0] * px)) + tv[0];
        qy[t] = fmaf(R[1][2], pz, fmaf(R[1][1], py, R[1][0] * px)) + tv[1];
        qz[t] = fmaf(R[2][2], pz, fmaf(R[2][1], py, R[2][0] * px)) + tv[2];
        q2[t] = (qx[t] * qx[t] + qy[t] * qy[t]) + qz[t] * qz[t];
        if (tid < 8 && valid) {
            size_t pf = (size_t)B * N * 3 + (size_t)(b * N + qg) * 3;
            out[pf + 0] = qx[t] - px;
            out[pf + 1] = qy[t] - py;
            out[pf + 2] = qz[t] - pz;
        }
    }

    float bd[QT][KNN]; int bi[QT][KNN];
    #pragma unroll
    for (int t = 0; t < QT; ++t)
        #pragma unroll
        for (int k = 0; k < KNN; ++k) { bd[t][k] = FLT_MAX; bi[t][k] = INT_MAX; }

    // ---- scan reference points: each LDS point amortized over QT queries ----
    for (int tbase = 0; tbase < M; tbase += TM) {
        __syncthreads();
        #pragma unroll
        for (int k = 0; k < TM / 256; ++k) {
            int jl = tid + k * 256;
            int m  = tbase + jl;
            float4 v;
            if (m < M) {
                const float* p = pc1 + (size_t)(b * M + m) * 3;
                float x = p[0], y = p[1], z = p[2];
                v = make_float4(x, y, z, (x * x + y * y) + z * z);
            } else {
                v = make_float4(0.f, 0.f, 0.f, FLT_MAX);
            }
            tile[jl] = v;
        }
        __syncthreads();

        #pragma unroll 2
        for (int i = 0; i < TM / 32; ++i) {
            float4 v = tile[i * 32 + s];
            int m = tbase + i * 32 + s;
            #pragma unroll
            for (int t = 0; t < QT; ++t) {
                float cross = fmaf(qz[t], v.z, fmaf(qy[t], v.y, qx[t] * v.x));
                float d2 = fmaf(-2.0f, cross, q2[t] + v.w); // matches ref rounding
                if (d2 < bd[t][2]) {   // strict <: ascending m keeps lowest idx
                    if (d2 < bd[t][1]) {
                        bd[t][2] = bd[t][1]; bi[t][2] = bi[t][1];
                        if (d2 < bd[t][0]) { bd[t][1] = bd[t][0]; bi[t][1] = bi[t][0];
                                             bd[t][0] = d2; bi[t][0] = m; }
                        else               { bd[t][1] = d2; bi[t][1] = m; }
                    } else { bd[t][2] = d2; bi[t][2] = m; }
                }
            }
        }
    }

    // ---- in-wave butterfly merge of 8 stripes (lane bits 3..5) ----
    #pragma unroll
    for (int t = 0; t < QT; ++t) {
        float d0 = bd[t][0], d1 = bd[t][1], d2v = bd[t][2];
        int   i0 = bi[t][0], i1 = bi[t][1], i2v = bi[t][2];
        #pragma unroll
        for (int msk = 8; msk <= 32; msk <<= 1) {
            float od0 = __shfl_xor(d0, msk), od1 = __shfl_xor(d1, msk), od2 = __shfl_xor(d2v, msk);
            int   oi0 = __shfl_xor(i0, msk), oi1 = __shfl_xor(i1, msk), oi2 = __shfl_xor(i2v, msk);
            ins3(od0, oi0, d0, d1, d2v, i0, i1, i2v);
            ins3(od1, oi1, d0, d1, d2v, i0, i1, i2v);
            ins3(od2, oi2, d0, d1, d2v, i0, i1, i2v);
        }
        if (((tid >> 3) & 7) == 0) {        // stripe-in-wave 0 holds wave partial
            int w = tid >> 6;
            mdl[w][qlane][t][0] = d0;  mdl[w][qlane][t][1] = d1;  mdl[w][qlane][t][2] = d2v;
            mil[w][qlane][t][0] = i0;  mil[w][qlane][t][1] = i1;  mil[w][qlane][t][2] = i2v;
        }
    }
    __syncthreads();

    // ---- final cross-wave merge + weights + flow gather (one thread/query) ----
    if (tid < QPB) {
        int qg0 = qb + tid;
        if (qg0 < N) {
            int ql = tid >> 2, t = tid & 3;
            float d0 = FLT_MAX, d1 = FLT_MAX, d2v = FLT_MAX;
            int   i0 = INT_MAX, i1 = INT_MAX, i2v = INT_MAX;
            #pragma unroll
            for (int w = 0; w < 4; ++w)
                #pragma unroll
                for (int k = 0; k < KNN; ++k)
                    ins3(mdl[w][ql][t][k], mil[w][ql][t][k], d0, d1, d2v, i0, i1, i2v);

            float dd0 = sqrtf(fmaxf(d0, 0.f));
            float dd1 = sqrtf(fmaxf(d1, 0.f));
            float dd2 = sqrtf(fmaxf(d2v, 0.f));
            float w0 = 1.0f / (dd0 + 1e-8f);
            float w1 = 1.0f / (dd1 + 1e-8f);
            float w2 = 1.0f / (dd2 + 1e-8f);
            float wsum = (w0 + w1) + w2;
            w0 /= wsum; w1 /= wsum; w2 /= wsum;

            const float* f0 = flow1 + (size_t)(b * M + i0) * 3;
            const float* f1 = flow1 + (size_t)(b * M + i1) * 3;
            const float* f2 = flow1 + (size_t)(b * M + i2v) * 3;

            const size_t ob = (size_t)(b * N + qg0) * 3;
            #pragma unroll
            for (int c = 0; c < 3; ++c) {
                float p0 = w0 * f0[c];
                float p1 = w1 * f1[c];
                float p2 = w2 * f2[c];
                out[ob + c] = (p0 + p1) + p2;
            }
        }
    }
}

extern "C" void kernel_launch(void* const* d_in, const int* in_sizes, int n_in,
                              void* d_out, int out_size, void* d_ws, size_t ws_size,
                              hipStream_t stream) {
    const float* pc0   = (const float*)d_in[0];
    const float* pc1   = (const float*)d_in[1];
    const float* flow1 = (const float*)d_in[2];
    const float* pose0 = (const float*)d_in[3];
    const float* pose1 = (const float*)d_in[4];
    float* out = (float*)d_out;

    const int B = in_sizes[3] / 16;
    const int N = in_sizes[0] / (3 * B);
    const int M = in_sizes[1] / (3 * B);

    dim3 grid((N + QPB - 1) / QPB, B);
    knn_flow_kernel<<<grid, dim3(256), 0, stream>>>(pc0, pc1, flow1, pose0, pose1,
                                                    out, B, N, M);
}